// Round 7
// baseline (1392.887 us; speedup 1.0000x reference)
//
#include <hip/hip_runtime.h>
#include <math.h>

typedef __bf16 bf16x8 __attribute__((ext_vector_type(8)));
typedef float f32x4 __attribute__((ext_vector_type(4)));

__device__ __forceinline__ unsigned short f2bf(float x) {
  unsigned int u = __builtin_bit_cast(unsigned int, x);
  unsigned int r = (u + 0x7fffu + ((u >> 16) & 1u)) >> 16;
  return (unsigned short)r;
}
__device__ __forceinline__ float bf2f(unsigned short u) {
  return __builtin_bit_cast(float, ((unsigned int)u) << 16);
}
__device__ __forceinline__ void async16(const void* g, void* l) {
  __builtin_amdgcn_global_load_lds(
      (const __attribute__((address_space(1))) void*)g,
      (__attribute__((address_space(3))) void*)l, 16, 0, 0);
}

// f32 -> bf16 (RNE), 8 elems/thread
__global__ __launch_bounds__(256) void cvt_bf16_k(const float* __restrict__ in,
                                                  unsigned short* __restrict__ out,
                                                  int n8) {
  const int i = blockIdx.x * 256 + threadIdx.x;
  if (i >= n8) return;
  const float4* p = (const float4*)in + (long)i * 2;
  const float4 v0 = p[0], v1 = p[1];
  alignas(16) unsigned short o[8] = {f2bf(v0.x), f2bf(v0.y), f2bf(v0.z), f2bf(v0.w),
                                     f2bf(v1.x), f2bf(v1.y), f2bf(v1.z), f2bf(v1.w)};
  *(uint4*)(out + (long)i * 8) = *(uint4*)o;
}

// rope table: tab[t*64+i] = {cos,sin}(t * 10000^(-(4i+1)/128)), t<2048, i<64
__global__ __launch_bounds__(256) void rope_tab(float2* __restrict__ tab) {
  const int id = blockIdx.x * 256 + threadIdx.x;
  const int t = id >> 6, i = id & 63;
  const float kf = 13.287712379549449f / 128.f;  // log2(10000)/128
  const float a = (float)t * exp2f(-(4.f * (float)i + 1.f) * kf);
  float s, c;
  sincosf(a, &s, &c);
  tab[id] = make_float2(c, s);
}

// ---------------------------------------------------------------------------
// gemm1: 256x256 tile, BK=32, 8 waves (2M x 4N), TWO LDS buffers (64 KiB) ->
// 2 blocks/CU co-resident (R6's 3-buf/96KB forced 1 block/CU + dispatch tail:
// MfmaUtil 29%). Depth-1 counted-vmcnt pipeline (R4-validated): stage next
// K-tile -> vmcnt(4) -> barrier -> 12 ds_read_b128 + 32 MFMA -> barrier.
// Per-MFMA ratios vs 128^2: ds_read 0.375 (was 0.5), stage and barriers
// halved. Zero-conflict XOR swizzle (R6-validated, conflicts 1.26e7 -> 0):
// both-sides elem-XOR ((row>>1)&3)<<3, pre-swizzled global src + linear LDS
// dest (G21-safe with global_load_lds), reads apply same XOR.
// C[m,n] = sum_k A[m,k]*B[n,k]; A bf16 [4096,K], B bf16 [6144,K].
// n<4096 -> q/k bf16 rows stride 4096; n>=4096 -> V transposed Vt[bh][d][t].
// Grid dim3(24,16) = 384 wgs (384%8==0), XCD-chunk swizzled; all co-resident.
// ---------------------------------------------------------------------------
__global__ __launch_bounds__(512, 4) void gemm256_qkv(
    const unsigned short* __restrict__ A, const unsigned short* __restrict__ B,
    unsigned short* __restrict__ C, unsigned short* __restrict__ Vt, int K) {
  __shared__ unsigned short As[2][256 * 32];  // 32 KiB
  __shared__ unsigned short Bs[2][256 * 32];  // 32 KiB
  const int tid = threadIdx.x;
  const int lane = tid & 63;
  const int w = tid >> 6;  // 0..7
  const int wm = w >> 2, wn = w & 3;
  const int fr = lane & 15, fq = lane >> 4;
  const int nbx = gridDim.x;
  const int nwg = nbx * (int)gridDim.y;
  int bid = (int)blockIdx.y * nbx + (int)blockIdx.x;
  bid = (bid & 7) * (nwg >> 3) + (bid >> 3);
  const long m0 = (long)(bid / nbx) * 256;
  const long n0 = (long)(bid % nbx) * 256;
  // staging: 512 thr x 16 B = 128 rows/round; 2 rounds per matrix per K-tile
  const int srow_ = tid >> 2;       // 0..127
  const int scol_ = (tid & 3) * 8;  // elem col base
  auto stage = [&](int buf, int kt) {
#pragma unroll
    for (int r = 0; r < 2; r++) {
      const int row = r * 128 + srow_;
      const int col = scol_ ^ (((row >> 1) & 3) << 3);  // inverse-swizzled src
      async16(A + (m0 + row) * (long)K + kt * 32 + col, &As[buf][row * 32 + scol_]);
      async16(B + (n0 + row) * (long)K + kt * 32 + col, &Bs[buf][row * 32 + scol_]);
    }
  };
  f32x4 acc[8][4] = {};
  const int NT = K >> 5;
  int cur = 0;
  stage(0, 0);
  for (int t = 0; t < NT; ++t) {
    if (t + 1 < NT) {
      stage(cur ^ 1, t + 1);  // prefetch next K-tile (4 loads)
      asm volatile("s_waitcnt vmcnt(4)" ::: "memory");  // tile t resident
    } else {
      asm volatile("s_waitcnt vmcnt(0)" ::: "memory");
    }
    __builtin_amdgcn_s_barrier();
    asm volatile("" ::: "memory");
    bf16x8 a[8], b[4];
#pragma unroll
    for (int i = 0; i < 8; i++) {
      const int row = wm * 128 + i * 16 + fr;
      a[i] = *(const bf16x8*)&As[cur][row * 32 +
                                      ((fq * 8) ^ (((row >> 1) & 3) << 3))];
    }
#pragma unroll
    for (int j = 0; j < 4; j++) {
      const int row = wn * 64 + j * 16 + fr;
      b[j] = *(const bf16x8*)&Bs[cur][row * 32 +
                                      ((fq * 8) ^ (((row >> 1) & 3) << 3))];
    }
    __builtin_amdgcn_s_setprio(1);
#pragma unroll
    for (int i = 0; i < 8; i++)
#pragma unroll
      for (int j = 0; j < 4; j++)
        acc[i][j] =
            __builtin_amdgcn_mfma_f32_16x16x32_bf16(a[i], b[j], acc[i][j], 0, 0, 0);
    __builtin_amdgcn_s_setprio(0);
    asm volatile("" ::: "memory");
    __builtin_amdgcn_s_barrier();  // all reads of buf[cur] done -> overwrite ok
    asm volatile("" ::: "memory");
    cur ^= 1;
  }
  if (n0 < 4096) {  // q/k rows, stride 4096
#pragma unroll
    for (int i = 0; i < 8; i++)
#pragma unroll
      for (int j = 0; j < 4; j++)
#pragma unroll
        for (int r = 0; r < 4; r++) {
          const long m = m0 + wm * 128 + i * 16 + fq * 4 + r;
          const long n = n0 + wn * 64 + j * 16 + fr;
          C[m * 4096 + n] = f2bf(acc[i][j][r]);
        }
  } else {  // V transposed: Vt[bh][d][t], 4 consecutive t per lane
#pragma unroll
    for (int i = 0; i < 8; i++)
#pragma unroll
      for (int j = 0; j < 4; j++) {
        const long n = n0 + wn * 64 + j * 16 + fr;
        const long vb = ((m0 >> 11) * 16 + ((n - 4096) >> 7)) * (128L * 2048);
        const int d = (int)(n - 4096) & 127;
        const int tt = ((int)m0 & 2047) + wm * 128 + i * 16 + fq * 4;
        alignas(8) unsigned short o[4] = {f2bf(acc[i][j][0]), f2bf(acc[i][j][1]),
                                          f2bf(acc[i][j][2]), f2bf(acc[i][j][3])};
        *(uint2*)&Vt[vb + (long)d * 2048 + tt] = *(uint2*)o;
      }
  }
}

// gemm2: 128^2 tile, depth-1 counted-vmcnt double buffer (R4-validated).
// C f32 [M,N] = sum_k A[m,k]*B[n,k].
__global__ __launch_bounds__(256) void gemm128(
    const unsigned short* __restrict__ A, const unsigned short* __restrict__ B,
    float* __restrict__ C, int M, int N, int K) {
  __shared__ unsigned short As[2][128 * 32];
  __shared__ unsigned short Bs[2][128 * 32];
  const int tid = threadIdx.x;
  const int lane = tid & 63;
  const int w = tid >> 6;
  const int wr = w >> 1, wc = w & 1;
  const int fr = lane & 15, fq = lane >> 4;
  const int nbx = gridDim.x;
  const int nwg = nbx * (int)gridDim.y;
  int bid = (int)blockIdx.y * nbx + (int)blockIdx.x;
  bid = (bid & 7) * (nwg >> 3) + (bid >> 3);
  const long m0 = (long)(bid / nbx) * 128;
  const long n0 = (long)(bid % nbx) * 128;
  const int sr = lane >> 2, sc = (lane & 3) * 8;
  f32x4 acc[4][4] = {};
  auto stage = [&](int buf, int k0) {
#pragma unroll
    for (int i = 0; i < 2; i++) {
      const int r = (w * 2 + i) * 16 + sr;
      async16(A + (m0 + r) * (long)K + k0 + sc, &As[buf][(w * 2 + i) * 512]);
      async16(B + (n0 + r) * (long)K + k0 + sc, &Bs[buf][(w * 2 + i) * 512]);
    }
  };
  int cur = 0;
  stage(0, 0);
  for (int k0 = 0; k0 < K; k0 += 32) {
    if (k0 + 32 < K) {
      stage(cur ^ 1, k0 + 32);
      asm volatile("s_waitcnt vmcnt(4)" ::: "memory");
    } else {
      asm volatile("s_waitcnt vmcnt(0)" ::: "memory");
    }
    __builtin_amdgcn_s_barrier();
    asm volatile("" ::: "memory");
    bf16x8 a[4], b[4];
#pragma unroll
    for (int i = 0; i < 4; i++)
      a[i] = *(const bf16x8*)&As[cur][(wr * 64 + i * 16 + fr) * 32 + fq * 8];
#pragma unroll
    for (int j = 0; j < 4; j++)
      b[j] = *(const bf16x8*)&Bs[cur][(wc * 64 + j * 16 + fr) * 32 + fq * 8];
#pragma unroll
    for (int i = 0; i < 4; i++)
#pragma unroll
      for (int j = 0; j < 4; j++)
        acc[i][j] =
            __builtin_amdgcn_mfma_f32_16x16x32_bf16(a[i], b[j], acc[i][j], 0, 0, 0);
    asm volatile("" ::: "memory");
    __builtin_amdgcn_s_barrier();
    asm volatile("" ::: "memory");
    cur ^= 1;
  }
#pragma unroll
  for (int i = 0; i < 4; i++)
#pragma unroll
    for (int j = 0; j < 4; j++)
#pragma unroll
      for (int r = 0; r < 4; r++) {
        const long m = m0 + wr * 64 + i * 16 + fq * 4 + r;
        const long n = n0 + wc * 64 + j * 16 + fr;
        C[m * N + n] = acc[i][j][r];
      }
}

// in-place on bf16 q,k rows (stride 4096): RMSNorm (g f32) + RoPE via table
__global__ __launch_bounds__(256) void rms_rope(unsigned short* __restrict__ qkv,
                                                const float* __restrict__ g,
                                                const float2* __restrict__ tab) {
  const int m = blockIdx.x;  // 0..4095
  const int t = m & 2047;
  const int tid = threadIdx.x;
  const int lane = tid & 63, w = tid >> 6;
  unsigned short* row = qkv + (long)m * 4096;
  const int base = tid * 8;
  alignas(16) unsigned short qs[8], ks[8];
  *(uint4*)qs = *(const uint4*)(row + base);
  *(uint4*)ks = *(const uint4*)(row + 2048 + base);
  float qv[8], kv[8];
  float sq = 0.f, sk = 0.f;
#pragma unroll
  for (int j = 0; j < 8; j++) {
    qv[j] = bf2f(qs[j]);
    kv[j] = bf2f(ks[j]);
    sq += qv[j] * qv[j];
    sk += kv[j] * kv[j];
  }
#pragma unroll
  for (int off = 1; off < 64; off <<= 1) {
    sq += __shfl_xor(sq, off);
    sk += __shfl_xor(sk, off);
  }
  __shared__ float red[2][4];
  if (lane == 0) {
    red[0][w] = sq;
    red[1][w] = sk;
  }
  __syncthreads();
  sq = red[0][0] + red[0][1] + red[0][2] + red[0][3];
  sk = red[1][0] + red[1][1] + red[1][2] + red[1][3];
  const float rq = rsqrtf(sq * (1.f / 2048.f) + 1e-6f);
  const float rk = rsqrtf(sk * (1.f / 2048.f) + 1e-6f);
  float qn[8], kn[8];
#pragma unroll
  for (int j = 0; j < 8; j++) {
    const float gg = g[base + j];
    qn[j] = qv[j] * rq * gg;
    kn[j] = kv[j] * rk * gg;
  }
  const float2* tp = tab + t * 64 + (base & 63);
  alignas(16) unsigned short qo[8], ko[8];
#pragma unroll
  for (int p = 0; p < 8; p += 2) {
    const float2 cs0 = tp[p];
    const float2 cs1 = tp[p + 1];
    qo[p] = f2bf(qn[p] * cs0.x - qn[p + 1] * cs0.y);
    qo[p + 1] = f2bf(qn[p + 1] * cs1.x + qn[p] * cs1.y);
    ko[p] = f2bf(kn[p] * cs0.x - kn[p + 1] * cs0.y);
    ko[p + 1] = f2bf(kn[p + 1] * cs1.x + kn[p] * cs1.y);
  }
  *(uint4*)(row + base) = *(uint4*)qo;
  *(uint4*)(row + 2048 + base) = *(uint4*)ko;
}

// flash attention, QBLK=128 x KVBLK=64, 8 waves (512 thr), 2 blocks/CU
// (unchanged; counted-vmcnt double-buffered staging, swizzled LDS,
// per-wave P, deferred l_i reduce, setprio).
__global__ __launch_bounds__(512, 4) void attn64(
    const unsigned short* __restrict__ QKV, const unsigned short* __restrict__ VT,
    unsigned short* __restrict__ Y) {
  const int bid = blockIdx.x;
  const int r_ = bid & 7, s_ = bid >> 3;
  const int slot = s_ >> 4, jj = s_ & 15;
  const int bh = r_ * 4 + slot;
  const int qt = (jj & 1) ? 15 - (jj >> 1) : (jj >> 1);
  const int b = bh >> 4, h = bh & 15;
  const int tid = threadIdx.x, lane = tid & 63, w = tid >> 6;
  const int fr = lane & 15, fq = lane >> 4;
  __shared__ unsigned short Kl[2][64 * 128];
  __shared__ unsigned short Vl[2][128 * 64];
  __shared__ unsigned short Pl[8][16 * 64];
  char* Pb = (char*)&Pl[w][0];
  const long tokbase = (long)b * 2048;
  const unsigned short* Qp = QKV + tokbase * 4096 + h * 128;
  const unsigned short* Kp = Qp + 2048;
  const unsigned short* Vg = VT + (long)bh * (128 * 2048);
  const int qbase = qt * 128;
  bf16x8 aq[4];
  {
    const unsigned short* qp = Qp + (long)(qbase + w * 16 + fr) * 4096 + fq * 8;
#pragma unroll
    for (int ks = 0; ks < 4; ks++) aq[ks] = *(const bf16x8*)(qp + ks * 32);
  }
  const int kR = tid >> 4, kC = (tid & 15) * 8;
  const int vR = tid >> 3, vC = (tid & 7) * 8;
  auto stage = [&](unsigned short* Kd, unsigned short* Vd, int kt) {
#pragma unroll
    for (int i = 0; i < 2; i++) {
      const int rowK = i * 32 + kR;
      async16(Kp + (long)(kt * 64 + rowK) * 4096 + (kC ^ ((rowK & 7) << 3)),
              Kd + i * 4096 + tid * 8);
      const int rowV = i * 64 + vR;
      async16(Vg + (long)rowV * 2048 + kt * 64 + (vC ^ ((rowV & 7) << 3)),
              Vd + i * 4096 + tid * 8);
    }
  };
  float m_i[4], l_i[4];
#pragma unroll
  for (int r = 0; r < 4; r++) {
    m_i[r] = -1e30f;
    l_i[r] = 0.f;
  }
  f32x4 accO[8] = {};
  const float scale = 0.08838834764831845f;
  const int ktmax = 2 * qt + 1;
  int cur = 0;
  stage(Kl[0], Vl[0], 0);
  for (int kt = 0; kt <= ktmax; kt++) {
    if (kt < ktmax) {
      stage(Kl[cur ^ 1], Vl[cur ^ 1], kt + 1);
      asm volatile("s_waitcnt vmcnt(4)" ::: "memory");
    } else {
      asm volatile("s_waitcnt vmcnt(0)" ::: "memory");
    }
    __builtin_amdgcn_s_barrier();
    asm volatile("" ::: "memory");
    const unsigned short* Kc = Kl[cur];
    const unsigned short* Vc = Vl[cur];
    f32x4 accS[4] = {};
    __builtin_amdgcn_s_setprio(1);
#pragma unroll
    for (int n = 0; n < 4; n++) {
      const int rowK = n * 16 + fr;
#pragma unroll
      for (int ks = 0; ks < 4; ks++) {
        bf16x8 bk =
            *(const bf16x8*)&Kc[rowK * 128 + ((ks * 32 + fq * 8) ^ ((fr & 7) << 3))];
        accS[n] = __builtin_amdgcn_mfma_f32_16x16x32_bf16(aq[ks], bk, accS[n], 0, 0, 0);
      }
    }
    __builtin_amdgcn_s_setprio(0);
    if (kt * 64 + 63 > qbase + w * 16) {
#pragma unroll
      for (int n = 0; n < 4; n++)
#pragma unroll
        for (int r = 0; r < 4; r++) {
          const int key = kt * 64 + n * 16 + fr;
          const int qq = qbase + w * 16 + fq * 4 + r;
          accS[n][r] = (key > qq) ? -1e30f : accS[n][r] * scale;
        }
    } else {
#pragma unroll
      for (int n = 0; n < 4; n++)
#pragma unroll
        for (int r = 0; r < 4; r++) accS[n][r] *= scale;
    }
    float mx[4];
    bool need = false;
#pragma unroll
    for (int r = 0; r < 4; r++) {
      float m = fmaxf(fmaxf(accS[0][r], accS[1][r]), fmaxf(accS[2][r], accS[3][r]));
#pragma unroll
      for (int off = 1; off < 16; off <<= 1) m = fmaxf(m, __shfl_xor(m, off));
      mx[r] = m;
      need |= (m > m_i[r] + 8.f);
    }
    if (__any(need)) {
#pragma unroll
      for (int r = 0; r < 4; r++) {
        const float mnew = fmaxf(m_i[r], mx[r]);
        const float alpha = __expf(m_i[r] - mnew);
        m_i[r] = mnew;
        l_i[r] *= alpha;
#pragma unroll
        for (int ds = 0; ds < 8; ds++) accO[ds][r] *= alpha;
      }
    }
#pragma unroll
    for (int n = 0; n < 4; n++)
#pragma unroll
      for (int r = 0; r < 4; r++) accS[n][r] = __expf(accS[n][r] - m_i[r]);
#pragma unroll
    for (int r = 0; r < 4; r++)
      l_i[r] += accS[0][r] + accS[1][r] + accS[2][r] + accS[3][r];
#pragma unroll
    for (int n = 0; n < 4; n++)
#pragma unroll
      for (int r = 0; r < 4; r++) {
        const int row = fq * 4 + r;
        const int byte = row * 128 + ((n * 32 + fr * 2) ^ ((row & 7) << 4));
        *(unsigned short*)(Pb + byte) = f2bf(accS[n][r]);
      }
    __builtin_amdgcn_s_setprio(1);
#pragma unroll
    for (int ks = 0; ks < 2; ks++) {
      bf16x8 ap =
          *(const bf16x8*)(Pb + fr * 128 + ((ks * 64 + fq * 16) ^ ((fr & 7) << 4)));
#pragma unroll
      for (int ds = 0; ds < 8; ds++) {
        bf16x8 bv = *(const bf16x8*)&Vc[(ds * 16 + fr) * 64 +
                                        ((ks * 32 + fq * 8) ^ ((fr & 7) << 3))];
        accO[ds] = __builtin_amdgcn_mfma_f32_16x16x32_bf16(ap, bv, accO[ds], 0, 0, 0);
      }
    }
    __builtin_amdgcn_s_setprio(0);
    asm volatile("" ::: "memory");
    __builtin_amdgcn_s_barrier();
    asm volatile("" ::: "memory");
    cur ^= 1;
  }
#pragma unroll
  for (int r = 0; r < 4; r++) {
#pragma unroll
    for (int off = 1; off < 16; off <<= 1) l_i[r] += __shfl_xor(l_i[r], off);
    l_i[r] = 1.f / l_i[r];
  }
#pragma unroll
  for (int ds = 0; ds < 8; ds++)
#pragma unroll
    for (int r = 0; r < 4; r++) {
      const long trow = tokbase + qbase + w * 16 + fq * 4 + r;
      Y[trow * 2048 + h * 128 + ds * 16 + fr] = f2bf(accO[ds][r] * l_i[r]);
    }
}

extern "C" void kernel_launch(void* const* d_in, const int* in_sizes, int n_in,
                              void* d_out, int out_size, void* d_ws, size_t ws_size,
                              hipStream_t stream) {
  (void)out_size;
  (void)ws_size;
  const float *x = 0, *Wq = 0, *Wp = 0, *g = 0;
  for (int i = 0; i < n_in; i++) {
    switch (in_sizes[i]) {
      case 8388608: x = (const float*)d_in[i]; break;    // [2,2048,2048]
      case 12582912: Wq = (const float*)d_in[i]; break;  // [6144,2048]
      case 4194304: Wp = (const float*)d_in[i]; break;   // [2048,2048]
      case 2048: g = (const float*)d_in[i]; break;       // [2048]
    }
  }
  if (!x) x = (const float*)d_in[0];
  if (!Wq) Wq = (const float*)d_in[1];
  if (!Wp) Wp = (const float*)d_in[2];
  if (!g) g = (const float*)d_in[3];
  float* out = (float*)d_out;
  char* ws = (char*)d_ws;
  // workspace layout (97 MiB total):
  //   [0,32Mi)    qkv16: q,k rows bf16, stride 4096
  //   [32,48Mi)   VtG: V transposed [32 bh][128 d][2048 t] bf16
  //   [48,64Mi)   Y (xb lives here first; dead before attn writes Y)
  //   [64,88Mi)   Wqb bf16; [88,96Mi) Wpb bf16; [96,97Mi) rope table
  unsigned short* qkv16 = (unsigned short*)ws;
  unsigned short* VtG = (unsigned short*)(ws + 33554432);
  unsigned short* Y = (unsigned short*)(ws + 50331648);
  unsigned short* xb = Y;
  unsigned short* Wqb = (unsigned short*)(ws + 67108864);
  unsigned short* Wpb = (unsigned short*)(ws + 92274688);
  float2* tab = (float2*)(ws + 100663296);

  cvt_bf16_k<<<4096, 256, 0, stream>>>(x, xb, 1048576);
  cvt_bf16_k<<<6144, 256, 0, stream>>>(Wq, Wqb, 1572864);
  cvt_bf16_k<<<2048, 256, 0, stream>>>(Wp, Wpb, 524288);
  rope_tab<<<512, 256, 0, stream>>>(tab);
  gemm256_qkv<<<dim3(24, 16), 512, 0, stream>>>(xb, Wqb, qkv16, VtG, 2048);
  rms_rope<<<4096, 256, 0, stream>>>(qkv16, g, tab);
  attn64<<<512, 512, 0, stream>>>(qkv16, VtG, Y);  // overwrites xb (dead)
  gemm128<<<dim3(16, 32), 256, 0, stream>>>(Y, Wpb, out, 4096, 2048, 2048);
}

// Round 8
// 430.924 us; speedup vs baseline: 3.2323x; 3.2323x over previous
//
#include <hip/hip_runtime.h>
#include <math.h>

typedef __bf16 bf16x8 __attribute__((ext_vector_type(8)));
typedef float f32x4 __attribute__((ext_vector_type(4)));

__device__ __forceinline__ unsigned short f2bf(float x) {
  unsigned int u = __builtin_bit_cast(unsigned int, x);
  unsigned int r = (u + 0x7fffu + ((u >> 16) & 1u)) >> 16;
  return (unsigned short)r;
}
__device__ __forceinline__ float bf2f(unsigned short u) {
  return __builtin_bit_cast(float, ((unsigned int)u) << 16);
}
__device__ __forceinline__ void async16(const void* g, void* l) {
  __builtin_amdgcn_global_load_lds(
      (const __attribute__((address_space(1))) void*)g,
      (__attribute__((address_space(3))) void*)l, 16, 0, 0);
}

#define MEMFENCE asm volatile("" ::: "memory")
#define BARRIER                      \
  do {                               \
    MEMFENCE;                        \
    __builtin_amdgcn_s_barrier();    \
    MEMFENCE;                        \
  } while (0)

// f32 -> bf16 (RNE), 8 elems/thread
__global__ __launch_bounds__(256) void cvt_bf16_k(const float* __restrict__ in,
                                                  unsigned short* __restrict__ out,
                                                  int n8) {
  const int i = blockIdx.x * 256 + threadIdx.x;
  if (i >= n8) return;
  const float4* p = (const float4*)in + (long)i * 2;
  const float4 v0 = p[0], v1 = p[1];
  alignas(16) unsigned short o[8] = {f2bf(v0.x), f2bf(v0.y), f2bf(v0.z), f2bf(v0.w),
                                     f2bf(v1.x), f2bf(v1.y), f2bf(v1.z), f2bf(v1.w)};
  *(uint4*)(out + (long)i * 8) = *(uint4*)o;
}

// rope table: tab[t*64+i] = {cos,sin}(t * 10000^(-(4i+1)/128)), t<2048, i<64
__global__ __launch_bounds__(256) void rope_tab(float2* __restrict__ tab) {
  const int id = blockIdx.x * 256 + threadIdx.x;
  const int t = id >> 6, i = id & 63;
  const float kf = 13.287712379549449f / 128.f;  // log2(10000)/128
  const float a = (float)t * exp2f(-(4.f * (float)i + 1.f) * kf);
  float s, c;
  sincosf(a, &s, &c);
  tab[id] = make_float2(c, s);
}

// ---------------------------------------------------------------------------
// gemm1, 8-PHASE schedule (m201-class): 256x256 tile, BK=64 (2 K-tiles/iter),
// 8 waves (2M x 4N), LDS = 2 buf x 2 kk x [256][32] x {A,B} = 128 KiB,
// 1 block/CU (2 waves/SIMD). Per phase: {2 global_load_lds of one future
// half-tile | 8-or-4 ds_read_b128 | barrier | setprio + 16 MFMA | vmcnt(8) on
// even phases | barrier}. Steady state keeps 12 loads outstanding, vmcnt(8)
// retires the oldest 4 -- NEVER drains (the T3/T4 lever). Staging plan
// ph1..8 = t1kk1A, t1kk1B, t2kk0A, t2kk0B, t2kk1A, t2kk1B, t3kk0A, t3kk0B:
// every LDS region has >=1 full barrier between its last read and first
// overwrite (audited), and each region's loads retire 2 phases before use.
// Swizzle: R6-validated zero-conflict elem-XOR ((row>>1)&3)<<3, pre-swizzled
// global src + linear LDS dest (G21), same XOR on reads.
// __launch_bounds__(512) with NO min-waves arg (R7: ",4" forced 64 VGPR and
// spilled acc -> 3 GB scratch writes).
// C[m,n] = sum_k A[m,k]*B[n,k]; n<4096 -> q/k rows stride 4096; n>=4096 ->
// V transposed Vt[bh][d][t]. Grid dim3(24,16)=384 (384%8==0, XCD-swizzled).
// ---------------------------------------------------------------------------
__global__ __launch_bounds__(512) void gemm256_qkv(
    const unsigned short* __restrict__ A, const unsigned short* __restrict__ B,
    unsigned short* __restrict__ C, unsigned short* __restrict__ Vt, int K) {
  __shared__ unsigned short As[2][2][256 * 32];  // [buf][kk] 64 KiB
  __shared__ unsigned short Bs[2][2][256 * 32];  // 64 KiB
  const int tid = threadIdx.x;
  const int lane = tid & 63;
  const int w = tid >> 6;  // 0..7
  const int wm = w >> 2, wn = w & 3;
  const int fr = lane & 15, fq = lane >> 4;
  const int nbx = gridDim.x;
  const int nwg = nbx * (int)gridDim.y;
  int bid = (int)blockIdx.y * nbx + (int)blockIdx.x;
  bid = (bid & 7) * (nwg >> 3) + (bid >> 3);
  const long m0 = (long)(bid / nbx) * 256;
  const long n0 = (long)(bid % nbx) * 256;
  // staging: one call = 512 thr x 16 B = 128 rows of one [.][32] subtile
  const int srow = tid >> 2;       // 0..127
  const int scol = (tid & 3) * 8;  // elem col within 32-elem row
  auto stgA = [&](int buf, int kk, int t, int r) {
    const int row = r * 128 + srow;
    const int col = scol ^ (((row >> 1) & 3) << 3);  // inverse swizzle on src
    async16(A + (m0 + row) * (long)K + t * 64 + kk * 32 + col,
            &As[buf][kk][row * 32 + scol]);
  };
  auto stgB = [&](int buf, int kk, int t, int r) {
    const int row = r * 128 + srow;
    const int col = scol ^ (((row >> 1) & 3) << 3);
    async16(B + (n0 + row) * (long)K + t * 64 + kk * 32 + col,
            &Bs[buf][kk][row * 32 + scol]);
  };
  f32x4 acc[8][4] = {};
  bf16x8 bfr[4];
  auto loadA = [&](const unsigned short* Ab, int ih, bf16x8* a) {
#pragma unroll
    for (int i2 = 0; i2 < 4; i2++) {
      const int row = wm * 128 + (ih * 4 + i2) * 16 + fr;
      a[i2] = *(const bf16x8*)&Ab[row * 32 + ((fq * 8) ^ (((row >> 1) & 3) << 3))];
    }
  };
  auto loadB = [&](const unsigned short* Bb) {
#pragma unroll
    for (int j = 0; j < 4; j++) {
      const int row = wn * 64 + j * 16 + fr;
      bfr[j] = *(const bf16x8*)&Bb[row * 32 + ((fq * 8) ^ (((row >> 1) & 3) << 3))];
    }
  };
  auto mma = [&](bf16x8* a, int ih) {
    __builtin_amdgcn_s_setprio(1);
#pragma unroll
    for (int i2 = 0; i2 < 4; i2++)
#pragma unroll
      for (int j = 0; j < 4; j++)
        acc[ih * 4 + i2][j] = __builtin_amdgcn_mfma_f32_16x16x32_bf16(
            a[i2], bfr[j], acc[ih * 4 + i2][j], 0, 0, 0);
    __builtin_amdgcn_s_setprio(0);
  };
  const int NT = K >> 6;  // 64-wide K-tiles; K=2048 -> 32 (even)
  // prologue: t0 kk0+kk1 -> buf0, t1 kk0 -> buf1kk0; retire t0kk0 (vmcnt 8)
  stgA(0, 0, 0, 0); stgA(0, 0, 0, 1); stgB(0, 0, 0, 0); stgB(0, 0, 0, 1);
  stgA(0, 1, 0, 0); stgA(0, 1, 0, 1); stgB(0, 1, 0, 0); stgB(0, 1, 0, 1);
  stgA(1, 0, 1, 0); stgA(1, 0, 1, 1); stgB(1, 0, 1, 0); stgB(1, 0, 1, 1);
  asm volatile("s_waitcnt vmcnt(8)" ::: "memory");
  BARRIER;
  for (int it = 0; it < (NT >> 1); ++it) {
    const int t0 = 2 * it, t1 = t0 + 1;
    const bool s23 = (t0 + 2 < NT);
    bf16x8 a[4];
    // ph1: read buf0kk0 (ih0 + B); stage t1kk1-A -> As[1][1]
    stgA(1, 1, t1, 0); stgA(1, 1, t1, 1);
    loadA(&As[0][0][0], 0, a); loadB(&Bs[0][0][0]);
    BARRIER; mma(a, 0); BARRIER;
    // ph2: read buf0kk0 ih1; stage t1kk1-B
    stgB(1, 1, t1, 0); stgB(1, 1, t1, 1);
    loadA(&As[0][0][0], 1, a);
    BARRIER; mma(a, 1);
    asm volatile("s_waitcnt vmcnt(8)" ::: "memory");  // retire t0kk1
    BARRIER;
    // ph3: read buf0kk1 (ih0 + B); stage t2kk0-A (overwrites As[0][0], free)
    if (s23) { stgA(0, 0, t0 + 2, 0); stgA(0, 0, t0 + 2, 1); }
    loadA(&As[0][1][0], 0, a); loadB(&Bs[0][1][0]);
    BARRIER; mma(a, 0); BARRIER;
    // ph4: read buf0kk1 ih1; stage t2kk0-B
    if (s23) { stgB(0, 0, t0 + 2, 0); stgB(0, 0, t0 + 2, 1); }
    loadA(&As[0][1][0], 1, a);
    BARRIER; mma(a, 1);
    if (s23)  // retire t1kk0 (needed ph5)
      asm volatile("s_waitcnt vmcnt(8)" ::: "memory");
    else
      asm volatile("s_waitcnt vmcnt(4)" ::: "memory");
    BARRIER;
    // ph5: read buf1kk0 (ih0 + B); stage t2kk1-A
    if (s23) { stgA(0, 1, t0 + 2, 0); stgA(0, 1, t0 + 2, 1); }
    loadA(&As[1][0][0], 0, a); loadB(&Bs[1][0][0]);
    BARRIER; mma(a, 0); BARRIER;
    // ph6: read buf1kk0 ih1; stage t2kk1-B
    if (s23) { stgB(0, 1, t0 + 2, 0); stgB(0, 1, t0 + 2, 1); }
    loadA(&As[1][0][0], 1, a);
    BARRIER; mma(a, 1);
    if (s23)  // retire t1kk1 (needed ph7)
      asm volatile("s_waitcnt vmcnt(8)" ::: "memory");
    else
      asm volatile("s_waitcnt vmcnt(0)" ::: "memory");
    BARRIER;
    // ph7: read buf1kk1 (ih0 + B); stage t3kk0-A
    if (s23) { stgA(1, 0, t0 + 3, 0); stgA(1, 0, t0 + 3, 1); }
    loadA(&As[1][1][0], 0, a); loadB(&Bs[1][1][0]);
    BARRIER; mma(a, 0); BARRIER;
    // ph8: read buf1kk1 ih1; stage t3kk0-B
    if (s23) { stgB(1, 0, t0 + 3, 0); stgB(1, 0, t0 + 3, 1); }
    loadA(&As[1][1][0], 1, a);
    BARRIER; mma(a, 1);
    asm volatile("s_waitcnt vmcnt(8)" ::: "memory");  // retire t2kk0 (next ph1)
    BARRIER;
  }
  if (n0 < 4096) {  // q/k rows, stride 4096
#pragma unroll
    for (int i = 0; i < 8; i++)
#pragma unroll
      for (int j = 0; j < 4; j++)
#pragma unroll
        for (int r = 0; r < 4; r++) {
          const long m = m0 + wm * 128 + i * 16 + fq * 4 + r;
          const long n = n0 + wn * 64 + j * 16 + fr;
          C[m * 4096 + n] = f2bf(acc[i][j][r]);
        }
  } else {  // V transposed: Vt[bh][d][t], 4 consecutive t per lane
#pragma unroll
    for (int i = 0; i < 8; i++)
#pragma unroll
      for (int j = 0; j < 4; j++) {
        const long n = n0 + wn * 64 + j * 16 + fr;
        const long vb = ((m0 >> 11) * 16 + ((n - 4096) >> 7)) * (128L * 2048);
        const int d = (int)(n - 4096) & 127;
        const int tt = ((int)m0 & 2047) + wm * 128 + i * 16 + fq * 4;
        alignas(8) unsigned short o[4] = {f2bf(acc[i][j][0]), f2bf(acc[i][j][1]),
                                          f2bf(acc[i][j][2]), f2bf(acc[i][j][3])};
        *(uint2*)&Vt[vb + (long)d * 2048 + tt] = *(uint2*)o;
      }
  }
}

// gemm2: 128^2 tile, depth-1 counted-vmcnt double buffer (R4-validated).
// C f32 [M,N] = sum_k A[m,k]*B[n,k].
__global__ __launch_bounds__(256) void gemm128(
    const unsigned short* __restrict__ A, const unsigned short* __restrict__ B,
    float* __restrict__ C, int M, int N, int K) {
  __shared__ unsigned short As[2][128 * 32];
  __shared__ unsigned short Bs[2][128 * 32];
  const int tid = threadIdx.x;
  const int lane = tid & 63;
  const int w = tid >> 6;
  const int wr = w >> 1, wc = w & 1;
  const int fr = lane & 15, fq = lane >> 4;
  const int nbx = gridDim.x;
  const int nwg = nbx * (int)gridDim.y;
  int bid = (int)blockIdx.y * nbx + (int)blockIdx.x;
  bid = (bid & 7) * (nwg >> 3) + (bid >> 3);
  const long m0 = (long)(bid / nbx) * 128;
  const long n0 = (long)(bid % nbx) * 128;
  const int sr = lane >> 2, sc = (lane & 3) * 8;
  f32x4 acc[4][4] = {};
  auto stage = [&](int buf, int k0) {
#pragma unroll
    for (int i = 0; i < 2; i++) {
      const int r = (w * 2 + i) * 16 + sr;
      async16(A + (m0 + r) * (long)K + k0 + sc, &As[buf][(w * 2 + i) * 512]);
      async16(B + (n0 + r) * (long)K + k0 + sc, &Bs[buf][(w * 2 + i) * 512]);
    }
  };
  int cur = 0;
  stage(0, 0);
  for (int k0 = 0; k0 < K; k0 += 32) {
    if (k0 + 32 < K) {
      stage(cur ^ 1, k0 + 32);
      asm volatile("s_waitcnt vmcnt(4)" ::: "memory");
    } else {
      asm volatile("s_waitcnt vmcnt(0)" ::: "memory");
    }
    BARRIER;
    bf16x8 a[4], b[4];
#pragma unroll
    for (int i = 0; i < 4; i++)
      a[i] = *(const bf16x8*)&As[cur][(wr * 64 + i * 16 + fr) * 32 + fq * 8];
#pragma unroll
    for (int j = 0; j < 4; j++)
      b[j] = *(const bf16x8*)&Bs[cur][(wc * 64 + j * 16 + fr) * 32 + fq * 8];
#pragma unroll
    for (int i = 0; i < 4; i++)
#pragma unroll
      for (int j = 0; j < 4; j++)
        acc[i][j] =
            __builtin_amdgcn_mfma_f32_16x16x32_bf16(a[i], b[j], acc[i][j], 0, 0, 0);
    BARRIER;
    cur ^= 1;
  }
#pragma unroll
  for (int i = 0; i < 4; i++)
#pragma unroll
    for (int j = 0; j < 4; j++)
#pragma unroll
      for (int r = 0; r < 4; r++) {
        const long m = m0 + wr * 64 + i * 16 + fq * 4 + r;
        const long n = n0 + wc * 64 + j * 16 + fr;
        C[m * N + n] = acc[i][j][r];
      }
}

// in-place on bf16 q,k rows (stride 4096): RMSNorm (g f32) + RoPE via table
__global__ __launch_bounds__(256) void rms_rope(unsigned short* __restrict__ qkv,
                                                const float* __restrict__ g,
                                                const float2* __restrict__ tab) {
  const int m = blockIdx.x;  // 0..4095
  const int t = m & 2047;
  const int tid = threadIdx.x;
  const int lane = tid & 63, w = tid >> 6;
  unsigned short* row = qkv + (long)m * 4096;
  const int base = tid * 8;
  alignas(16) unsigned short qs[8], ks[8];
  *(uint4*)qs = *(const uint4*)(row + base);
  *(uint4*)ks = *(const uint4*)(row + 2048 + base);
  float qv[8], kv[8];
  float sq = 0.f, sk = 0.f;
#pragma unroll
  for (int j = 0; j < 8; j++) {
    qv[j] = bf2f(qs[j]);
    kv[j] = bf2f(ks[j]);
    sq += qv[j] * qv[j];
    sk += kv[j] * kv[j];
  }
#pragma unroll
  for (int off = 1; off < 64; off <<= 1) {
    sq += __shfl_xor(sq, off);
    sk += __shfl_xor(sk, off);
  }
  __shared__ float red[2][4];
  if (lane == 0) {
    red[0][w] = sq;
    red[1][w] = sk;
  }
  __syncthreads();
  sq = red[0][0] + red[0][1] + red[0][2] + red[0][3];
  sk = red[1][0] + red[1][1] + red[1][2] + red[1][3];
  const float rq = rsqrtf(sq * (1.f / 2048.f) + 1e-6f);
  const float rk = rsqrtf(sk * (1.f / 2048.f) + 1e-6f);
  float qn[8], kn[8];
#pragma unroll
  for (int j = 0; j < 8; j++) {
    const float gg = g[base + j];
    qn[j] = qv[j] * rq * gg;
    kn[j] = kv[j] * rk * gg;
  }
  const float2* tp = tab + t * 64 + (base & 63);
  alignas(16) unsigned short qo[8], ko[8];
#pragma unroll
  for (int p = 0; p < 8; p += 2) {
    const float2 cs0 = tp[p];
    const float2 cs1 = tp[p + 1];
    qo[p] = f2bf(qn[p] * cs0.x - qn[p + 1] * cs0.y);
    qo[p + 1] = f2bf(qn[p + 1] * cs1.x + qn[p] * cs1.y);
    ko[p] = f2bf(kn[p] * cs0.x - kn[p + 1] * cs0.y);
    ko[p + 1] = f2bf(kn[p + 1] * cs1.x + kn[p] * cs1.y);
  }
  *(uint4*)(row + base) = *(uint4*)qo;
  *(uint4*)(row + 2048 + base) = *(uint4*)ko;
}

// flash attention, QBLK=128 x KVBLK=64, 8 waves (512 thr), 2 blocks/CU
// (unchanged; counted-vmcnt double-buffered staging, swizzled LDS,
// per-wave P, deferred l_i reduce, setprio).
__global__ __launch_bounds__(512, 4) void attn64(
    const unsigned short* __restrict__ QKV, const unsigned short* __restrict__ VT,
    unsigned short* __restrict__ Y) {
  const int bid = blockIdx.x;
  const int r_ = bid & 7, s_ = bid >> 3;
  const int slot = s_ >> 4, jj = s_ & 15;
  const int bh = r_ * 4 + slot;
  const int qt = (jj & 1) ? 15 - (jj >> 1) : (jj >> 1);
  const int b = bh >> 4, h = bh & 15;
  const int tid = threadIdx.x, lane = tid & 63, w = tid >> 6;
  const int fr = lane & 15, fq = lane >> 4;
  __shared__ unsigned short Kl[2][64 * 128];
  __shared__ unsigned short Vl[2][128 * 64];
  __shared__ unsigned short Pl[8][16 * 64];
  char* Pb = (char*)&Pl[w][0];
  const long tokbase = (long)b * 2048;
  const unsigned short* Qp = QKV + tokbase * 4096 + h * 128;
  const unsigned short* Kp = Qp + 2048;
  const unsigned short* Vg = VT + (long)bh * (128 * 2048);
  const int qbase = qt * 128;
  bf16x8 aq[4];
  {
    const unsigned short* qp = Qp + (long)(qbase + w * 16 + fr) * 4096 + fq * 8;
#pragma unroll
    for (int ks = 0; ks < 4; ks++) aq[ks] = *(const bf16x8*)(qp + ks * 32);
  }
  const int kR = tid >> 4, kC = (tid & 15) * 8;
  const int vR = tid >> 3, vC = (tid & 7) * 8;
  auto stage = [&](unsigned short* Kd, unsigned short* Vd, int kt) {
#pragma unroll
    for (int i = 0; i < 2; i++) {
      const int rowK = i * 32 + kR;
      async16(Kp + (long)(kt * 64 + rowK) * 4096 + (kC ^ ((rowK & 7) << 3)),
              Kd + i * 4096 + tid * 8);
      const int rowV = i * 64 + vR;
      async16(Vg + (long)rowV * 2048 + kt * 64 + (vC ^ ((rowV & 7) << 3)),
              Vd + i * 4096 + tid * 8);
    }
  };
  float m_i[4], l_i[4];
#pragma unroll
  for (int r = 0; r < 4; r++) {
    m_i[r] = -1e30f;
    l_i[r] = 0.f;
  }
  f32x4 accO[8] = {};
  const float scale = 0.08838834764831845f;
  const int ktmax = 2 * qt + 1;
  int cur = 0;
  stage(Kl[0], Vl[0], 0);
  for (int kt = 0; kt <= ktmax; kt++) {
    if (kt < ktmax) {
      stage(Kl[cur ^ 1], Vl[cur ^ 1], kt + 1);
      asm volatile("s_waitcnt vmcnt(4)" ::: "memory");
    } else {
      asm volatile("s_waitcnt vmcnt(0)" ::: "memory");
    }
    BARRIER;
    const unsigned short* Kc = Kl[cur];
    const unsigned short* Vc = Vl[cur];
    f32x4 accS[4] = {};
    __builtin_amdgcn_s_setprio(1);
#pragma unroll
    for (int n = 0; n < 4; n++) {
      const int rowK = n * 16 + fr;
#pragma unroll
      for (int ks = 0; ks < 4; ks++) {
        bf16x8 bk =
            *(const bf16x8*)&Kc[rowK * 128 + ((ks * 32 + fq * 8) ^ ((fr & 7) << 3))];
        accS[n] = __builtin_amdgcn_mfma_f32_16x16x32_bf16(aq[ks], bk, accS[n], 0, 0, 0);
      }
    }
    __builtin_amdgcn_s_setprio(0);
    if (kt * 64 + 63 > qbase + w * 16) {
#pragma unroll
      for (int n = 0; n < 4; n++)
#pragma unroll
        for (int r = 0; r < 4; r++) {
          const int key = kt * 64 + n * 16 + fr;
          const int qq = qbase + w * 16 + fq * 4 + r;
          accS[n][r] = (key > qq) ? -1e30f : accS[n][r] * scale;
        }
    } else {
#pragma unroll
      for (int n = 0; n < 4; n++)
#pragma unroll
        for (int r = 0; r < 4; r++) accS[n][r] *= scale;
    }
    float mx[4];
    bool need = false;
#pragma unroll
    for (int r = 0; r < 4; r++) {
      float m = fmaxf(fmaxf(accS[0][r], accS[1][r]), fmaxf(accS[2][r], accS[3][r]));
#pragma unroll
      for (int off = 1; off < 16; off <<= 1) m = fmaxf(m, __shfl_xor(m, off));
      mx[r] = m;
      need |= (m > m_i[r] + 8.f);
    }
    if (__any(need)) {
#pragma unroll
      for (int r = 0; r < 4; r++) {
        const float mnew = fmaxf(m_i[r], mx[r]);
        const float alpha = __expf(m_i[r] - mnew);
        m_i[r] = mnew;
        l_i[r] *= alpha;
#pragma unroll
        for (int ds = 0; ds < 8; ds++) accO[ds][r] *= alpha;
      }
    }
#pragma unroll
    for (int n = 0; n < 4; n++)
#pragma unroll
      for (int r = 0; r < 4; r++) accS[n][r] = __expf(accS[n][r] - m_i[r]);
#pragma unroll
    for (int r = 0; r < 4; r++)
      l_i[r] += accS[0][r] + accS[1][r] + accS[2][r] + accS[3][r];
#pragma unroll
    for (int n = 0; n < 4; n++)
#pragma unroll
      for (int r = 0; r < 4; r++) {
        const int row = fq * 4 + r;
        const int byte = row * 128 + ((n * 32 + fr * 2) ^ ((row & 7) << 4));
        *(unsigned short*)(Pb + byte) = f2bf(accS[n][r]);
      }
    __builtin_amdgcn_s_setprio(1);
#pragma unroll
    for (int ks = 0; ks < 2; ks++) {
      bf16x8 ap =
          *(const bf16x8*)(Pb + fr * 128 + ((ks * 64 + fq * 16) ^ ((fr & 7) << 4)));
#pragma unroll
      for (int ds = 0; ds < 8; ds++) {
        bf16x8 bv = *(const bf16x8*)&Vc[(ds * 16 + fr) * 64 +
                                        ((ks * 32 + fq * 8) ^ ((fr & 7) << 3))];
        accO[ds] = __builtin_amdgcn_mfma_f32_16x16x32_bf16(ap, bv, accO[ds], 0, 0, 0);
      }
    }
    __builtin_amdgcn_s_setprio(0);
    BARRIER;
    cur ^= 1;
  }
#pragma unroll
  for (int r = 0; r < 4; r++) {
#pragma unroll
    for (int off = 1; off < 16; off <<= 1) l_i[r] += __shfl_xor(l_i[r], off);
    l_i[r] = 1.f / l_i[r];
  }
#pragma unroll
  for (int ds = 0; ds < 8; ds++)
#pragma unroll
    for (int r = 0; r < 4; r++) {
      const long trow = tokbase + qbase + w * 16 + fq * 4 + r;
      Y[trow * 2048 + h * 128 + ds * 16 + fr] = f2bf(accO[ds][r] * l_i[r]);
    }
}

extern "C" void kernel_launch(void* const* d_in, const int* in_sizes, int n_in,
                              void* d_out, int out_size, void* d_ws, size_t ws_size,
                              hipStream_t stream) {
  (void)out_size;
  (void)ws_size;
  const float *x = 0, *Wq = 0, *Wp = 0, *g = 0;
  for (int i = 0; i < n_in; i++) {
    switch (in_sizes[i]) {
      case 8388608: x = (const float*)d_in[i]; break;    // [2,2048,2048]
      case 12582912: Wq = (const float*)d_in[i]; break;  // [6144,2048]
      case 4194304: Wp = (const float*)d_in[i]; break;   // [2048,2048]
      case 2048: g = (const float*)d_in[i]; break;       // [2048]
    }
  }
  if (!x) x = (const float*)d_in[0];
  if (!Wq) Wq = (const float*)d_in[1];
  if (!Wp) Wp = (const float*)d_in[2];
  if (!g) g = (const float*)d_in[3];
  float* out = (float*)d_out;
  char* ws = (char*)d_ws;
  // workspace layout (97 MiB total):
  //   [0,32Mi)    qkv16: q,k rows bf16, stride 4096
  //   [32,48Mi)   VtG: V transposed [32 bh][128 d][2048 t] bf16
  //   [48,64Mi)   Y (xb lives here first; dead before attn writes Y)
  //   [64,88Mi)   Wqb bf16; [88,96Mi) Wpb bf16; [96,97Mi) rope table
  unsigned short* qkv16 = (unsigned short*)ws;
  unsigned short* VtG = (unsigned short*)(ws + 33554432);
  unsigned short* Y = (unsigned short*)(ws + 50331648);
  unsigned short* xb = Y;
  unsigned short* Wqb = (unsigned short*)(ws + 67108864);
  unsigned short* Wpb = (unsigned short*)(ws + 92274688);
  float2* tab = (float2*)(ws + 100663296);

  cvt_bf16_k<<<4096, 256, 0, stream>>>(x, xb, 1048576);
  cvt_bf16_k<<<6144, 256, 0, stream>>>(Wq, Wqb, 1572864);
  cvt_bf16_k<<<2048, 256, 0, stream>>>(Wp, Wpb, 524288);
  rope_tab<<<512, 256, 0, stream>>>(tab);
  gemm256_qkv<<<dim3(24, 16), 512, 0, stream>>>(xb, Wqb, qkv16, VtG, 2048);
  rms_rope<<<4096, 256, 0, stream>>>(qkv16, g, tab);
  attn64<<<512, 512, 0, stream>>>(qkv16, VtG, Y);  // overwrites xb (dead)
  gemm128<<<dim3(16, 32), 256, 0, stream>>>(Y, Wpb, out, 4096, 2048, 2048);
}

// Round 10
// 419.997 us; speedup vs baseline: 3.3164x; 1.0260x over previous
//
#include <hip/hip_runtime.h>
#include <math.h>

typedef __bf16 bf16x8 __attribute__((ext_vector_type(8)));
typedef float f32x4 __attribute__((ext_vector_type(4)));

__device__ __forceinline__ unsigned short f2bf(float x) {
  unsigned int u = __builtin_bit_cast(unsigned int, x);
  unsigned int r = (u + 0x7fffu + ((u >> 16) & 1u)) >> 16;
  return (unsigned short)r;
}
__device__ __forceinline__ float bf2f(unsigned short u) {
  return __builtin_bit_cast(float, ((unsigned int)u) << 16);
}
__device__ __forceinline__ void async16(const void* g, void* l) {
  __builtin_amdgcn_global_load_lds(
      (const __attribute__((address_space(1))) void*)g,
      (__attribute__((address_space(3))) void*)l, 16, 0, 0);
}

#define MEMFENCE asm volatile("" ::: "memory")
#define BARRIER                   \
  do {                            \
    MEMFENCE;                     \
    __builtin_amdgcn_s_barrier(); \
    MEMFENCE;                     \
  } while (0)

// ---------------------------------------------------------------------------
// prep: fused {x->bf16, Wq->bf16, Wp->bf16, rope table} in ONE dispatch.
// Cross-round bookkeeping showed ~13-15 us of overhead per launch boundary;
// fusing 4 independent prep kernels removes 3 boundaries (~40 us).
// Block ranges: [0,4096) x (8 f32/thr), [4096,10240) Wq, [10240,12288) Wp,
// [12288,12800) rope table tab[t*64+i] = {cos,sin}(t*10000^(-(4i+1)/128)).
// ---------------------------------------------------------------------------
__global__ __launch_bounds__(256) void prep(const float* __restrict__ x,
                                            const float* __restrict__ Wq,
                                            const float* __restrict__ Wp,
                                            unsigned short* __restrict__ xb,
                                            unsigned short* __restrict__ Wqb,
                                            unsigned short* __restrict__ Wpb,
                                            float2* __restrict__ tab) {
  const int b = blockIdx.x;
  const int tid = threadIdx.x;
  if (b < 12288) {
    const float* in;
    unsigned short* out;
    int i;
    if (b < 4096) {
      in = x; out = xb; i = b * 256 + tid;
    } else if (b < 10240) {
      in = Wq; out = Wqb; i = (b - 4096) * 256 + tid;
    } else {
      in = Wp; out = Wpb; i = (b - 10240) * 256 + tid;
    }
    const float4* p = (const float4*)in + (long)i * 2;
    const float4 v0 = p[0], v1 = p[1];
    alignas(16) unsigned short o[8] = {f2bf(v0.x), f2bf(v0.y), f2bf(v0.z),
                                       f2bf(v0.w), f2bf(v1.x), f2bf(v1.y),
                                       f2bf(v1.z), f2bf(v1.w)};
    *(uint4*)(out + (long)i * 8) = *(uint4*)o;
  } else {
    const int id = (b - 12288) * 256 + tid;
    const int t = id >> 6, i = id & 63;
    const float kf = 13.287712379549449f / 128.f;  // log2(10000)/128
    const float a = (float)t * exp2f(-(4.f * (float)i + 1.f) * kf);
    float s, c;
    sincosf(a, &s, &c);
    tab[id] = make_float2(c, s);
  }
}

// C[m,n] = sum_k A[m,k]*B[n,k]; A bf16 [M,K], B bf16 [N,K], f32 accumulate.
// R4-measured best gemm structure (132.7 us @ qkv shape, MfmaUtil 34.7%):
// 128^2 tile, 2-phase counted-vmcnt pipeline, double-buffered As/Bs, next
// K-tile's 4 global_load_lds issued BEFORE compute, s_waitcnt vmcnt(4) + raw
// s_barrier -> 4 prefetch loads stay in flight across the barrier; never
// drain to 0 in-loop. (R5 depth-2: neutral. R6/R8 256^2 2ph/8ph: worse --
// 1 block/CU + 384-block grid = 25% dispatch-tail idle.)
// Grid XCD-swizzled (nwg % 8 == 0; 1536 and 512 both qualify).
// MODE 0: C f32 [M,N].
// MODE 1 (qkv): n<4096 -> bf16 rows stride 4096 (q,k); n>=4096 -> V stored
//   TRANSPOSED into Vt[bh][d][t].
template <int MODE>
__global__ __launch_bounds__(256) void gemm_bf(
    const unsigned short* __restrict__ A, const unsigned short* __restrict__ B,
    void* __restrict__ Cp, unsigned short* __restrict__ Vt, int M, int N, int K) {
  __shared__ unsigned short As[2][128 * 32];  // 2 x 8 KiB
  __shared__ unsigned short Bs[2][128 * 32];  // 2 x 8 KiB
  const int tid = threadIdx.x;
  const int lane = tid & 63;
  const int w = tid >> 6;
  const int wr = w >> 1, wc = w & 1;
  const int fr = lane & 15, fq = lane >> 4;
  const int nbx = gridDim.x;
  const int nwg = nbx * (int)gridDim.y;
  int bid = (int)blockIdx.y * nbx + (int)blockIdx.x;
  bid = (bid & 7) * (nwg >> 3) + (bid >> 3);
  const long m0 = (long)(bid / nbx) * 128;
  const long n0 = (long)(bid % nbx) * 128;
  const int sr = lane >> 2, sc = (lane & 3) * 8;  // bf16: 16 rows/call
  f32x4 acc[4][4] = {};
  auto stage = [&](int buf, int k0) {
#pragma unroll
    for (int i = 0; i < 2; i++) {
      const int r = (w * 2 + i) * 16 + sr;
      async16(A + (m0 + r) * (long)K + k0 + sc, &As[buf][(w * 2 + i) * 512]);
      async16(B + (n0 + r) * (long)K + k0 + sc, &Bs[buf][(w * 2 + i) * 512]);
    }
  };
  int cur = 0;
  stage(0, 0);
  for (int k0 = 0; k0 < K; k0 += 32) {
    if (k0 + 32 < K) {
      stage(cur ^ 1, k0 + 32);  // prefetch next K-tile
      asm volatile("s_waitcnt vmcnt(4)" ::: "memory");  // cur tile staged
    } else {
      asm volatile("s_waitcnt vmcnt(0)" ::: "memory");
    }
    BARRIER;
    bf16x8 a[4], b[4];
#pragma unroll
    for (int i = 0; i < 4; i++)
      a[i] = *(const bf16x8*)&As[cur][(wr * 64 + i * 16 + fr) * 32 + fq * 8];
#pragma unroll
    for (int j = 0; j < 4; j++)
      b[j] = *(const bf16x8*)&Bs[cur][(wc * 64 + j * 16 + fr) * 32 + fq * 8];
#pragma unroll
    for (int i = 0; i < 4; i++)
#pragma unroll
      for (int j = 0; j < 4; j++)
        acc[i][j] =
            __builtin_amdgcn_mfma_f32_16x16x32_bf16(a[i], b[j], acc[i][j], 0, 0, 0);
    BARRIER;  // all reads of buf[cur] done -> safe to overwrite
    cur ^= 1;
  }
  if (MODE == 0) {
    float* C = (float*)Cp;
#pragma unroll
    for (int i = 0; i < 4; i++)
#pragma unroll
      for (int j = 0; j < 4; j++)
#pragma unroll
        for (int r = 0; r < 4; r++) {
          const long m = m0 + wr * 64 + i * 16 + fq * 4 + r;
          const long n = n0 + wc * 64 + j * 16 + fr;
          C[m * N + n] = acc[i][j][r];
        }
  } else if (n0 < 4096) {
    unsigned short* C = (unsigned short*)Cp;
#pragma unroll
    for (int i = 0; i < 4; i++)
#pragma unroll
      for (int j = 0; j < 4; j++)
#pragma unroll
        for (int r = 0; r < 4; r++) {
          const long m = m0 + wr * 64 + i * 16 + fq * 4 + r;
          const long n = n0 + wc * 64 + j * 16 + fr;
          C[m * 4096 + n] = f2bf(acc[i][j][r]);
        }
  } else {
    const long vb = ((m0 >> 11) * 16 + ((n0 - 4096) >> 7)) * (128L * 2048);
#pragma unroll
    for (int i = 0; i < 4; i++)
#pragma unroll
      for (int j = 0; j < 4; j++) {
        const int d = wc * 64 + j * 16 + fr;
        const int t = (int)(m0 & 2047) + wr * 64 + i * 16 + fq * 4;
        alignas(8) unsigned short o[4] = {f2bf(acc[i][j][0]), f2bf(acc[i][j][1]),
                                          f2bf(acc[i][j][2]), f2bf(acc[i][j][3])};
        *(uint2*)&Vt[vb + (long)d * 2048 + t] = *(uint2*)o;
      }
  }
}

// in-place on bf16 q,k rows (stride 4096): RMSNorm (g f32) + RoPE via table
__global__ __launch_bounds__(256) void rms_rope(unsigned short* __restrict__ qkv,
                                                const float* __restrict__ g,
                                                const float2* __restrict__ tab) {
  const int m = blockIdx.x;  // 0..4095
  const int t = m & 2047;
  const int tid = threadIdx.x;
  const int lane = tid & 63, w = tid >> 6;
  unsigned short* row = qkv + (long)m * 4096;
  const int base = tid * 8;
  alignas(16) unsigned short qs[8], ks[8];
  *(uint4*)qs = *(const uint4*)(row + base);
  *(uint4*)ks = *(const uint4*)(row + 2048 + base);
  float qv[8], kv[8];
  float sq = 0.f, sk = 0.f;
#pragma unroll
  for (int j = 0; j < 8; j++) {
    qv[j] = bf2f(qs[j]);
    kv[j] = bf2f(ks[j]);
    sq += qv[j] * qv[j];
    sk += kv[j] * kv[j];
  }
#pragma unroll
  for (int off = 1; off < 64; off <<= 1) {
    sq += __shfl_xor(sq, off);
    sk += __shfl_xor(sk, off);
  }
  __shared__ float red[2][4];
  if (lane == 0) {
    red[0][w] = sq;
    red[1][w] = sk;
  }
  __syncthreads();
  sq = red[0][0] + red[0][1] + red[0][2] + red[0][3];
  sk = red[1][0] + red[1][1] + red[1][2] + red[1][3];
  const float rq = rsqrtf(sq * (1.f / 2048.f) + 1e-6f);
  const float rk = rsqrtf(sk * (1.f / 2048.f) + 1e-6f);
  float qn[8], kn[8];
#pragma unroll
  for (int j = 0; j < 8; j++) {
    const float gg = g[base + j];
    qn[j] = qv[j] * rq * gg;
    kn[j] = kv[j] * rk * gg;
  }
  const float2* tp = tab + t * 64 + (base & 63);
  alignas(16) unsigned short qo[8], ko[8];
#pragma unroll
  for (int p = 0; p < 8; p += 2) {
    const float2 cs0 = tp[p];
    const float2 cs1 = tp[p + 1];
    qo[p] = f2bf(qn[p] * cs0.x - qn[p + 1] * cs0.y);
    qo[p + 1] = f2bf(qn[p + 1] * cs1.x + qn[p] * cs1.y);
    ko[p] = f2bf(kn[p] * cs0.x - kn[p + 1] * cs0.y);
    ko[p + 1] = f2bf(kn[p + 1] * cs1.x + kn[p] * cs1.y);
  }
  *(uint4*)(row + base) = *(uint4*)qo;
  *(uint4*)(row + 2048 + base) = *(uint4*)ko;
}

// flash attention, QBLK=128 x KVBLK=64, 8 waves (512 thr), 2 blocks/CU
// (unchanged; counted-vmcnt double-buffered staging, swizzled LDS,
// per-wave P, deferred l_i reduce, setprio).
__global__ __launch_bounds__(512, 4) void attn64(
    const unsigned short* __restrict__ QKV, const unsigned short* __restrict__ VT,
    unsigned short* __restrict__ Y) {
  const int bid = blockIdx.x;
  const int r_ = bid & 7, s_ = bid >> 3;
  const int slot = s_ >> 4, jj = s_ & 15;
  const int bh = r_ * 4 + slot;
  const int qt = (jj & 1) ? 15 - (jj >> 1) : (jj >> 1);
  const int b = bh >> 4, h = bh & 15;
  const int tid = threadIdx.x, lane = tid & 63, w = tid >> 6;
  const int fr = lane & 15, fq = lane >> 4;
  __shared__ unsigned short Kl[2][64 * 128];
  __shared__ unsigned short Vl[2][128 * 64];
  __shared__ unsigned short Pl[8][16 * 64];
  char* Pb = (char*)&Pl[w][0];
  const long tokbase = (long)b * 2048;
  const unsigned short* Qp = QKV + tokbase * 4096 + h * 128;
  const unsigned short* Kp = Qp + 2048;
  const unsigned short* Vg = VT + (long)bh * (128 * 2048);
  const int qbase = qt * 128;
  bf16x8 aq[4];
  {
    const unsigned short* qp = Qp + (long)(qbase + w * 16 + fr) * 4096 + fq * 8;
#pragma unroll
    for (int ks = 0; ks < 4; ks++) aq[ks] = *(const bf16x8*)(qp + ks * 32);
  }
  const int kR = tid >> 4, kC = (tid & 15) * 8;
  const int vR = tid >> 3, vC = (tid & 7) * 8;
  auto stage = [&](unsigned short* Kd, unsigned short* Vd, int kt) {
#pragma unroll
    for (int i = 0; i < 2; i++) {
      const int rowK = i * 32 + kR;
      async16(Kp + (long)(kt * 64 + rowK) * 4096 + (kC ^ ((rowK & 7) << 3)),
              Kd + i * 4096 + tid * 8);
      const int rowV = i * 64 + vR;
      async16(Vg + (long)rowV * 2048 + kt * 64 + (vC ^ ((rowV & 7) << 3)),
              Vd + i * 4096 + tid * 8);
    }
  };
  float m_i[4], l_i[4];
#pragma unroll
  for (int r = 0; r < 4; r++) {
    m_i[r] = -1e30f;
    l_i[r] = 0.f;
  }
  f32x4 accO[8] = {};
  const float scale = 0.08838834764831845f;
  const int ktmax = 2 * qt + 1;
  int cur = 0;
  stage(Kl[0], Vl[0], 0);
  for (int kt = 0; kt <= ktmax; kt++) {
    if (kt < ktmax) {
      stage(Kl[cur ^ 1], Vl[cur ^ 1], kt + 1);
      asm volatile("s_waitcnt vmcnt(4)" ::: "memory");
    } else {
      asm volatile("s_waitcnt vmcnt(0)" ::: "memory");
    }
    BARRIER;
    const unsigned short* Kc = Kl[cur];
    const unsigned short* Vc = Vl[cur];
    f32x4 accS[4] = {};
    __builtin_amdgcn_s_setprio(1);
#pragma unroll
    for (int n = 0; n < 4; n++) {
      const int rowK = n * 16 + fr;
#pragma unroll
      for (int ks = 0; ks < 4; ks++) {
        bf16x8 bk =
            *(const bf16x8*)&Kc[rowK * 128 + ((ks * 32 + fq * 8) ^ ((fr & 7) << 3))];
        accS[n] = __builtin_amdgcn_mfma_f32_16x16x32_bf16(aq[ks], bk, accS[n], 0, 0, 0);
      }
    }
    __builtin_amdgcn_s_setprio(0);
    if (kt * 64 + 63 > qbase + w * 16) {
#pragma unroll
      for (int n = 0; n < 4; n++)
#pragma unroll
        for (int r = 0; r < 4; r++) {
          const int key = kt * 64 + n * 16 + fr;
          const int qq = qbase + w * 16 + fq * 4 + r;
          accS[n][r] = (key > qq) ? -1e30f : accS[n][r] * scale;
        }
    } else {
#pragma unroll
      for (int n = 0; n < 4; n++)
#pragma unroll
        for (int r = 0; r < 4; r++) accS[n][r] *= scale;
    }
    float mx[4];
    bool need = false;
#pragma unroll
    for (int r = 0; r < 4; r++) {
      float m = fmaxf(fmaxf(accS[0][r], accS[1][r]), fmaxf(accS[2][r], accS[3][r]));
#pragma unroll
      for (int off = 1; off < 16; off <<= 1) m = fmaxf(m, __shfl_xor(m, off));
      mx[r] = m;
      need |= (m > m_i[r] + 8.f);
    }
    if (__any(need)) {
#pragma unroll
      for (int r = 0; r < 4; r++) {
        const float mnew = fmaxf(m_i[r], mx[r]);
        const float alpha = __expf(m_i[r] - mnew);
        m_i[r] = mnew;
        l_i[r] *= alpha;
#pragma unroll
        for (int ds = 0; ds < 8; ds++) accO[ds][r] *= alpha;
      }
    }
#pragma unroll
    for (int n = 0; n < 4; n++)
#pragma unroll
      for (int r = 0; r < 4; r++) accS[n][r] = __expf(accS[n][r] - m_i[r]);
#pragma unroll
    for (int r = 0; r < 4; r++)
      l_i[r] += accS[0][r] + accS[1][r] + accS[2][r] + accS[3][r];
#pragma unroll
    for (int n = 0; n < 4; n++)
#pragma unroll
      for (int r = 0; r < 4; r++) {
        const int row = fq * 4 + r;
        const int byte = row * 128 + ((n * 32 + fr * 2) ^ ((row & 7) << 4));
        *(unsigned short*)(Pb + byte) = f2bf(accS[n][r]);
      }
    __builtin_amdgcn_s_setprio(1);
#pragma unroll
    for (int ks = 0; ks < 2; ks++) {
      bf16x8 ap =
          *(const bf16x8*)(Pb + fr * 128 + ((ks * 64 + fq * 16) ^ ((fr & 7) << 4)));
#pragma unroll
      for (int ds = 0; ds < 8; ds++) {
        bf16x8 bv = *(const bf16x8*)&Vc[(ds * 16 + fr) * 64 +
                                        ((ks * 32 + fq * 8) ^ ((fr & 7) << 3))];
        accO[ds] = __builtin_amdgcn_mfma_f32_16x16x32_bf16(ap, bv, accO[ds], 0, 0, 0);
      }
    }
    __builtin_amdgcn_s_setprio(0);
    BARRIER;
    cur ^= 1;
  }
#pragma unroll
  for (int r = 0; r < 4; r++) {
#pragma unroll
    for (int off = 1; off < 16; off <<= 1) l_i[r] += __shfl_xor(l_i[r], off);
    l_i[r] = 1.f / l_i[r];
  }
#pragma unroll
  for (int ds = 0; ds < 8; ds++)
#pragma unroll
    for (int r = 0; r < 4; r++) {
      const long trow = tokbase + qbase + w * 16 + fq * 4 + r;
      Y[trow * 2048 + h * 128 + ds * 16 + fr] = f2bf(accO[ds][r] * l_i[r]);
    }
}

extern "C" void kernel_launch(void* const* d_in, const int* in_sizes, int n_in,
                              void* d_out, int out_size, void* d_ws, size_t ws_size,
                              hipStream_t stream) {
  (void)out_size;
  (void)ws_size;
  const float *x = 0, *Wq = 0, *Wp = 0, *g = 0;
  for (int i = 0; i < n_in; i++) {
    switch (in_sizes[i]) {
      case 8388608: x = (const float*)d_in[i]; break;    // [2,2048,2048]
      case 12582912: Wq = (const float*)d_in[i]; break;  // [6144,2048]
      case 4194304: Wp = (const float*)d_in[i]; break;   // [2048,2048]
      case 2048: g = (const float*)d_in[i]; break;       // [2048]
    }
  }
  if (!x) x = (const float*)d_in[0];
  if (!Wq) Wq = (const float*)d_in[1];
  if (!Wp) Wp = (const float*)d_in[2];
  if (!g) g = (const float*)d_in[3];
  float* out = (float*)d_out;
  char* ws = (char*)d_ws;
  // workspace layout (97 MiB total):
  //   [0,32Mi)    qkv16: q,k rows bf16, stride 4096
  //   [32,48Mi)   VtG: V transposed [32 bh][128 d][2048 t] bf16
  //   [48,64Mi)   Y (xb lives here first; dead before attn writes Y)
  //   [64,88Mi)   Wqb bf16; [88,96Mi) Wpb bf16; [96,97Mi) rope table
  unsigned short* qkv16 = (unsigned short*)ws;
  unsigned short* VtG = (unsigned short*)(ws + 33554432);
  unsigned short* Y = (unsigned short*)(ws + 50331648);
  unsigned short* xb = Y;
  unsigned short* Wqb = (unsigned short*)(ws + 67108864);
  unsigned short* Wpb = (unsigned short*)(ws + 92274688);
  float2* tab = (float2*)(ws + 100663296);

  prep<<<12800, 256, 0, stream>>>(x, Wq, Wp, xb, Wqb, Wpb, tab);
  gemm_bf<1><<<dim3(48, 32), 256, 0, stream>>>(xb, Wqb, qkv16, VtG, 4096, 6144,
                                               2048);
  rms_rope<<<4096, 256, 0, stream>>>(qkv16, g, tab);
  attn64<<<512, 512, 0, stream>>>(qkv16, VtG, Y);  // overwrites xb (dead)
  gemm_bf<0><<<dim3(16, 32), 256, 0, stream>>>(Y, Wpb, out, nullptr, 4096, 2048,
                                               2048);
}